// Round 14
// baseline (2944.802 us; speedup 1.0000x reference)
//
#include <hip/hip_runtime.h>
#include <math.h>

// Model_13348758356240 — R14: R13 resubmit with compile fix (no __global__
// lambdas in fallback; restored reduce_tanh_k). Main path identical to R13:
// R12 base + ticket-fused logits/argmax + combined h0/m0 init GEMM.

typedef __attribute__((ext_vector_type(8))) short bf16x8;
typedef __attribute__((ext_vector_type(4))) float f32x4;

#define B_ 128
#define L_ 49
#define D_ 2048
#define H_ 2048
#define E_ 512
#define KA_ 512
#define V_ 10000
#define T_ 20
#define ED_ 2560
#define KT_ 4608
#define KT2_ 2560
#define H4_ 8192
#define VP_ 10112

__device__ __forceinline__ void split1(float x, short* hi, short* lo){
  unsigned u = __float_as_uint(x);
  *hi = (short)(u >> 16);
  float r = x - __uint_as_float(u & 0xffff0000u);
  *lo = (short)(__float_as_uint(r) >> 16);
}
__device__ __forceinline__ void split8(float4 a, float4 b, bf16x8& h, bf16x8& l){
  float xs[8] = {a.x,a.y,a.z,a.w,b.x,b.y,b.z,b.w};
#pragma unroll
  for (int i=0;i<8;++i){
    unsigned u = __float_as_uint(xs[i]);
    h[i] = (short)(u>>16);
    float r = xs[i] - __uint_as_float(u & 0xffff0000u);
    l[i] = (short)(__float_as_uint(r)>>16);
  }
}

#define MFMA16(d,a,b,c) d = __builtin_amdgcn_mfma_f32_16x16x32_bf16(a,b,c,0,0,0)

__device__ __forceinline__ void gl_lds16(const short* g, char* l){
  __builtin_amdgcn_global_load_lds(
      (const __attribute__((address_space(1))) unsigned int*)g,
      (__attribute__((address_space(3))) unsigned int*)l, 16, 0, 0);
}

// ============ R8-proven GEMM: single-buffer LDS staging, dual-A sources ============
__global__ __launch_bounds__(256)
void gemm_lds(const short* __restrict__ A1h, const short* __restrict__ A1l, int lda1,
              const short* __restrict__ A2h, const short* __restrict__ A2l, int lda2,
              int ksplit,
              const short* __restrict__ Wh, const short* __restrict__ Wl, int ldw,
              float* __restrict__ Cp, int Mtot, int Np, int k_len)
{
  __shared__ __align__(16) char smem[65536];
  const int tid = threadIdx.x;
  const int wid = tid >> 6, lane = tid & 63;
  const int lr = lane & 15, lg = lane >> 4;
  const int m0 = blockIdx.z * 128;
  const int nblk = blockIdx.x * 128;
  const int kb0 = blockIdx.y * k_len;

  const int li8 = lane >> 3;
  const int kx  = 8 * ((lane & 7) ^ li8);

  f32x4 acc[8][2];
#pragma unroll
  for (int i=0;i<8;++i)
#pragma unroll
    for (int r=0;r<4;++r){ acc[i][0][r]=0.f; acc[i][1][r]=0.f; }

  const int rA = wid*32 + lr, rB = rA + 16;
  const int sw7 = lr & 7;

  for (int kt = 0; kt < k_len; kt += 64) {
    const int kb = kb0 + kt;
    if (wid == 0) {
#pragma unroll
      for (int j = 0; j < 16; ++j)
        gl_lds16(Wh + (long)(nblk + j*8 + li8)*ldw + kb + kx, smem + j*1024);
    } else if (wid == 1) {
#pragma unroll
      for (int j = 0; j < 16; ++j)
        gl_lds16(Wl + (long)(nblk + j*8 + li8)*ldw + kb + kx, smem + 16384 + j*1024);
    } else {
      const short *Ph, *Pl; int ldx, kc;
      if (kb < ksplit) { Ph = A1h; Pl = A1l; ldx = lda1; kc = kb; }
      else             { Ph = A2h; Pl = A2l; ldx = lda2; kc = kb - ksplit; }
      if (wid == 2) {
#pragma unroll
        for (int j = 0; j < 16; ++j)
          gl_lds16(Ph + (long)(m0 + j*8 + li8)*ldx + kc + kx, smem + 32768 + j*1024);
      } else {
#pragma unroll
        for (int j = 0; j < 16; ++j)
          gl_lds16(Pl + (long)(m0 + j*8 + li8)*ldx + kc + kx, smem + 49152 + j*1024);
      }
    }
    asm volatile("s_waitcnt vmcnt(0)");
    __syncthreads();

#pragma unroll
    for (int h = 0; h < 2; ++h) {
      const int c16 = (h<<2) + lg;
      const int swz = (c16 ^ sw7) << 4;
      const bf16x8 whA = *(const bf16x8*)(smem +         rA*128 + swz);
      const bf16x8 wlA = *(const bf16x8*)(smem + 16384 + rA*128 + swz);
      const bf16x8 whB = *(const bf16x8*)(smem +         rB*128 + swz);
      const bf16x8 wlB = *(const bf16x8*)(smem + 16384 + rB*128 + swz);
#pragma unroll
      for (int mt = 0; mt < 8; ++mt) {
        const int aoff = (mt*16 + lr)*128 + swz;
        const bf16x8 ah = *(const bf16x8*)(smem + 32768 + aoff);
        const bf16x8 al = *(const bf16x8*)(smem + 49152 + aoff);
        MFMA16(acc[mt][0], ah, whA, acc[mt][0]);
        MFMA16(acc[mt][1], ah, whB, acc[mt][1]);
        MFMA16(acc[mt][0], ah, wlA, acc[mt][0]);
        MFMA16(acc[mt][1], ah, wlB, acc[mt][1]);
        MFMA16(acc[mt][0], al, whA, acc[mt][0]);
        MFMA16(acc[mt][1], al, whB, acc[mt][1]);
      }
    }
    __syncthreads();
  }

  const long srow = (long)blockIdx.y * Mtot + m0;
#pragma unroll
  for (int mt=0; mt<8; ++mt)
#pragma unroll
    for (int nt=0; nt<2; ++nt){
      const int col = nblk + wid*32 + nt*16 + lr;
#pragma unroll
      for (int r=0; r<4; ++r)
        Cp[(srow + mt*16 + 4*lg + r)*Np + col] = acc[mt][nt][r];
    }
}

// ============ fallback GEMM: fp32 W, on-the-fly split ============
template<bool AF32>
__global__ __launch_bounds__(256)
void gemm_mfma(const void* Ahv, const void* Alv, int lda,
               const float* __restrict__ W1, int ldw1,
               const float* __restrict__ W2, int ldw2, int ksplit,
               float* __restrict__ Cp, int Mtot, int Np, int Nvalid, int k_len)
{
  const int tid = threadIdx.x;
  const int wid = tid >> 6, lane = tid & 63;
  const int lr = lane & 15, lg = lane >> 4;
  const int m0 = blockIdx.z * 128;
  const int nw = blockIdx.x * 128 + wid * 32;
  const int kb = blockIdx.y * k_len;

  int rowA = nw + lr;       if (rowA >= Nvalid) rowA = Nvalid - 1;
  int rowB = nw + 16 + lr;  if (rowB >= Nvalid) rowB = Nvalid - 1;

  f32x4 acc[8][2];
#pragma unroll
  for (int i=0;i<8;++i)
#pragma unroll
    for (int r=0;r<4;++r){ acc[i][0][r]=0.f; acc[i][1][r]=0.f; }

  for (int kk = 0; kk < k_len; kk += 32) {
    const int kg = kb + kk;
    const float *pA, *pB;
    if (W2 && kg >= ksplit) {
      pA = W2 + (long)rowA*ldw2 + (kg - ksplit) + 8*lg;
      pB = W2 + (long)rowB*ldw2 + (kg - ksplit) + 8*lg;
    } else {
      pA = W1 + (long)rowA*ldw1 + kg + 8*lg;
      pB = W1 + (long)rowB*ldw1 + kg + 8*lg;
    }
    bf16x8 whA, wlA, whB, wlB;
    split8(*(const float4*)pA, *(const float4*)(pA+4), whA, wlA);
    split8(*(const float4*)pB, *(const float4*)(pB+4), whB, wlB);

    bf16x8 ah[8], al[8];
    if constexpr (AF32) {
      const float* Af = (const float*)Ahv;
#pragma unroll
      for (int mt=0; mt<8; ++mt){
        const float* ap = Af + (long)(m0 + mt*16 + lr)*lda + kg + 8*lg;
        split8(*(const float4*)ap, *(const float4*)(ap+4), ah[mt], al[mt]);
      }
    } else {
      const short* Ah = (const short*)Ahv;
      const short* Al = (const short*)Alv;
#pragma unroll
      for (int mt=0; mt<8; ++mt){
        const long off = (long)(m0 + mt*16 + lr)*lda + kg + 8*lg;
        ah[mt] = *(const bf16x8*)(Ah + off);
        al[mt] = *(const bf16x8*)(Al + off);
      }
    }
#pragma unroll
    for (int mt=0; mt<8; ++mt){
      MFMA16(acc[mt][0], ah[mt], whA, acc[mt][0]);
      MFMA16(acc[mt][1], ah[mt], whB, acc[mt][1]);
      MFMA16(acc[mt][0], ah[mt], wlA, acc[mt][0]);
      MFMA16(acc[mt][1], ah[mt], wlB, acc[mt][1]);
      MFMA16(acc[mt][0], al[mt], whA, acc[mt][0]);
      MFMA16(acc[mt][1], al[mt], whB, acc[mt][1]);
    }
  }

  const long srow = (long)blockIdx.y * Mtot + m0;
#pragma unroll
  for (int mt=0; mt<8; ++mt)
#pragma unroll
    for (int nt=0; nt<2; ++nt){
      const int col = nw + nt*16 + lr;
#pragma unroll
      for (int r=0; r<4; ++r)
        Cp[(srow + mt*16 + 4*lg + r)*Np + col] = acc[mt][nt][r];
    }
}

// ============ prep kernels ============
__global__ __launch_bounds__(256)
void split_nt_k(const float* __restrict__ W, int src_ld, int Nv, int kcount,
                short* __restrict__ Wh, short* __restrict__ Wl, int ldo, int ko)
{
  const int n = blockIdx.y;
  const int k = blockIdx.x * 1024 + threadIdx.x * 4;
  if (k >= kcount) return;
  short4 hv, lv;
  if (n < Nv) {
    const float4 v = *(const float4*)&W[(long)n*src_ld + k];
    split1(v.x, &hv.x, &lv.x); split1(v.y, &hv.y, &lv.y);
    split1(v.z, &hv.z, &lv.z); split1(v.w, &hv.w, &lv.w);
  } else {
    hv.x=hv.y=hv.z=hv.w=0; lv.x=lv.y=lv.z=lv.w=0;
  }
  *(short4*)&Wh[(long)n*ldo + ko + k] = hv;
  *(short4*)&Wl[(long)n*ldo + ko + k] = lv;
}

__global__ __launch_bounds__(256)
void split_t_k(const float* __restrict__ in, int K, int N,
               short* __restrict__ Oh, short* __restrict__ Ol)
{
  __shared__ float t[64][65];
  const int tid = threadIdx.x;
  const int c0 = blockIdx.x * 64, r0 = blockIdx.y * 64;
  const int lx = tid & 63, ly = tid >> 6;
#pragma unroll
  for (int i = 0; i < 16; ++i)
    t[ly + 4*i][lx] = in[(long)(r0 + ly + 4*i) * N + c0 + lx];
  __syncthreads();
#pragma unroll
  for (int i = 0; i < 16; ++i) {
    short hh, ll;
    split1(t[lx][ly + 4*i], &hh, &ll);
    const long o = (long)(c0 + ly + 4*i) * K + r0 + lx;
    Oh[o] = hh; Ol[o] = ll;
  }
}

__global__ __launch_bounds__(256)
void split_plane_k(const float* __restrict__ in, long n,
                   short* __restrict__ oh, short* __restrict__ ol)
{
  const long i = ((long)blockIdx.x * 256 + threadIdx.x) * 4;
  if (i >= n) return;
  const float4 v = *(const float4*)&in[i];
  short4 hv, lv;
  split1(v.x, &hv.x, &lv.x); split1(v.y, &hv.y, &lv.y);
  split1(v.z, &hv.z, &lv.z); split1(v.w, &hv.w, &lv.w);
  *(short4*)&oh[i] = hv;
  *(short4*)&ol[i] = lv;
}

__global__ __launch_bounds__(256)
void transpose_f32(const float* __restrict__ in, int R, int C, float* __restrict__ out)
{
  __shared__ float t[64][65];
  const int tid = threadIdx.x;
  const int c0 = blockIdx.x * 64, r0 = blockIdx.y * 64;
  const int lx = tid & 63, ly = tid >> 6;
#pragma unroll
  for (int i = 0; i < 16; ++i)
    t[ly + 4*i][lx] = in[(long)(r0 + ly + 4*i) * C + c0 + lx];
  __syncthreads();
#pragma unroll
  for (int i = 0; i < 16; ++i)
    out[(long)(c0 + ly + 4*i) * R + r0 + lx] = t[lx][ly + 4*i];
}

template<int S>
__global__ void reduce_sp_k(const float4* __restrict__ p, float4* __restrict__ sp)
{
  const long i = (long)blockIdx.x * 256 + threadIdx.x;
  const long s = 802816;
  float4 r; r.x = 0.f; r.y = 0.f; r.z = 0.f; r.w = 0.f;
#pragma unroll
  for (int sl = 0; sl < S; ++sl) {
    const float4 v = p[i + sl*s];
    r.x += v.x; r.y += v.y; r.z += v.z; r.w += v.w;
  }
  sp[i] = r;
}

template<int S>
__global__ __launch_bounds__(256)
void gred_k(const float* __restrict__ prt, const float* __restrict__ b_ih,
            const float* __restrict__ b_hh, float* __restrict__ gconst)
{
  const int idx = blockIdx.x * 256 + threadIdx.x;
  const int n = idx & (H4_ - 1);
  float s = b_ih[n] + b_hh[n];
#pragma unroll
  for (int sl = 0; sl < S; ++sl) s += prt[(long)sl * (B_*H4_) + idx];
  gconst[idx] = s;
}

// S-slice tanh reduce (h0/m0 fallback path)
template<int S>
__global__ __launch_bounds__(256)
void reduce_tanh_k(const float* __restrict__ gp, float* __restrict__ out,
                   short* __restrict__ ohi, short* __restrict__ olo)
{
  const int idx = blockIdx.x * 256 + threadIdx.x;
  float s = 0.f;
#pragma unroll
  for (int sl = 0; sl < S; ++sl) s += gp[(long)sl * (B_*H_) + idx];
  s = tanhf(s);
  out[idx] = s;
  if (ohi) split1(s, &ohi[idx], &olo[idx]);
}

// combined h0/m0 reduce: prt [S][B][4096], cols 0..2047 -> h, 2048.. -> m
template<int S>
__global__ __launch_bounds__(256)
void init_hm_reduce_k(const float* __restrict__ prt, float* __restrict__ h,
                      float* __restrict__ m, short* __restrict__ h_hi,
                      short* __restrict__ h_lo)
{
  const int idx = blockIdx.x * 256 + threadIdx.x;   // 0 .. B*4096-1
  const int b = idx >> 12, n = idx & 4095;
  float s = 0.f;
#pragma unroll
  for (int sl = 0; sl < S; ++sl) s += prt[((long)sl * B_ + b) * 4096 + n];
  s = tanhf(s);
  if (n < H_) {
    const long o = (long)b * H_ + n;
    h[o] = s;
    split1(s, &h_hi[o], &h_lo[o]);
  } else {
    m[(long)b * H_ + (n - H_)] = s;
  }
}

// ============ step kernels ============
__global__ void init_k(int* tok, int* tickets) {
  const int i = threadIdx.x + blockIdx.x * 256;
  if (i < B_) tok[i] = 1; // START_IDX
  if (i < T_ * B_) tickets[i] = 0;
}

__global__ void gather_emb_k(const float* __restrict__ embed, const int* __restrict__ tok,
                             short* __restrict__ xe_hi, short* __restrict__ xe_lo)
{
  const int b = blockIdx.x, tid = threadIdx.x;
  const int tk = tok[b];
  const float* e = embed + (long)tk * E_;
  for (int i = tid; i < E_; i += 256) split1(e[i], &xe_hi[(long)b*E_ + i], &xe_lo[(long)b*E_ + i]);
}

__global__ void gather_xh_k(const float* __restrict__ embed, const float* __restrict__ global_,
                            const short* __restrict__ h_hi, const short* __restrict__ h_lo,
                            const int* __restrict__ tok,
                            short* __restrict__ xh_hi, short* __restrict__ xh_lo)
{
  const int b = blockIdx.x, tid = threadIdx.x;
  const int tk = tok[b];
  short* rh = xh_hi + (long)b * KT_;
  short* rl = xh_lo + (long)b * KT_;
  const float* e = embed + (long)tk * E_;
  for (int i = tid; i < E_; i += 256) split1(e[i], &rh[i], &rl[i]);
  for (int i = tid; i < D_; i += 256) split1(global_[(long)b * D_ + i], &rh[E_ + i], &rl[E_ + i]);
  for (int i = tid; i < H_; i += 256) { rh[ED_ + i] = h_hi[(long)b * H_ + i]; rl[ED_ + i] = h_lo[(long)b * H_ + i]; }
}

template<int S>
__global__ __launch_bounds__(256)
void lstm_reduce_k(const float* __restrict__ gp, const float* __restrict__ gconst,
                   const float* __restrict__ b1, const float* __restrict__ b2,
                   float* __restrict__ h, float* __restrict__ m,
                   short* __restrict__ h_hi, short* __restrict__ h_lo)
{
  const int idx = blockIdx.x * 256 + threadIdx.x;
  const int b = idx >> 11, n = idx & (H_ - 1);
  float g[4];
#pragma unroll
  for (int j = 0; j < 4; ++j) {
    float s = gconst ? gconst[(long)b * H4_ + j*H_ + n] : (b1[j*H_ + n] + b2[j*H_ + n]);
#pragma unroll
    for (int sl = 0; sl < S; ++sl) s += gp[((long)sl * B_ + b) * H4_ + j*H_ + n];
    g[j] = s;
  }
  const float si = 1.f / (1.f + expf(-g[0]));
  const float sf = 1.f / (1.f + expf(-g[1]));
  const float gg = tanhf(g[2]);
  const float so = 1.f / (1.f + expf(-g[3]));
  const float mn = sf * m[idx] + si * gg;
  const float hn = so * tanhf(mn);
  m[idx] = mn; h[idx] = hn;
  split1(hn, &h_hi[idx], &h_lo[idx]);
}

// fused attention: hg-reduce + z + softmax + c + comb. grid (B_, 2).
__global__ __launch_bounds__(256)
void attn_one(const float* __restrict__ hgp, const float* __restrict__ sp,
              const float* __restrict__ w_h, const float* __restrict__ spatial,
              const float* __restrict__ h,
              short* __restrict__ a_hi, short* __restrict__ a_lo)
{
  const int b = blockIdx.x, dh = blockIdx.y, tid = threadIdx.x;
  const int wv = tid >> 6, lane = tid & 63;
  __shared__ float hgs[KA_];
  __shared__ float whs[KA_];
  __shared__ float zs[L_];
  __shared__ float alph[L_];
  for (int i = tid; i < KA_; i += 256) {
    float s = 0.f;
#pragma unroll
    for (int sl = 0; sl < 32; ++sl) s += hgp[((long)sl * B_ + b) * KA_ + i];
    hgs[i] = s; whs[i] = w_h[i];
  }
  __syncthreads();
  const int k0 = lane * 8;
  for (int l = wv; l < L_; l += 4) {
    const float4* spv = (const float4*)(sp + ((long)b * L_ + l) * KA_ + k0);
    const float4 s1 = spv[0], s2 = spv[1];
    float s = whs[k0]   * tanhf(s1.x + hgs[k0])
            + whs[k0+1] * tanhf(s1.y + hgs[k0+1])
            + whs[k0+2] * tanhf(s1.z + hgs[k0+2])
            + whs[k0+3] * tanhf(s1.w + hgs[k0+3])
            + whs[k0+4] * tanhf(s2.x + hgs[k0+4])
            + whs[k0+5] * tanhf(s2.y + hgs[k0+5])
            + whs[k0+6] * tanhf(s2.z + hgs[k0+6])
            + whs[k0+7] * tanhf(s2.w + hgs[k0+7]);
#pragma unroll
    for (int off = 32; off > 0; off >>= 1) s += __shfl_down(s, off);
    if (lane == 0) zs[l] = s;
  }
  __syncthreads();
  if (wv == 0) {
    float v = (lane < L_) ? zs[lane] : -INFINITY;
    float mx = v;
#pragma unroll
    for (int off = 32; off > 0; off >>= 1) mx = fmaxf(mx, __shfl_xor(mx, off));
    float e = (lane < L_) ? expf(v - mx) : 0.f;
    float sum = e;
#pragma unroll
    for (int off = 32; off > 0; off >>= 1) sum += __shfl_xor(sum, off);
    if (lane < L_) alph[lane] = e / sum;
  }
  __syncthreads();
  const int d4 = dh * 256 + tid;
  const float4* sp4 = (const float4*)spatial;
  float4 acc = ((const float4*)h)[(long)b * 512 + d4];
#pragma unroll 7
  for (int l = 0; l < L_; ++l) {
    const float w = alph[l];
    const float4 v = sp4[((long)b * L_ + l) * 512 + d4];
    acc.x = fmaf(w, v.x, acc.x); acc.y = fmaf(w, v.y, acc.y);
    acc.z = fmaf(w, v.z, acc.z); acc.w = fmaf(w, v.w, acc.w);
  }
  short4 hv, lv;
  split1(acc.x, &hv.x, &lv.x); split1(acc.y, &hv.y, &lv.y);
  split1(acc.z, &hv.z, &lv.z); split1(acc.w, &hv.w, &lv.w);
  *(short4*)&a_hi[(long)b * D_ + d4*4] = hv;
  *(short4*)&a_lo[(long)b * D_ + d4*4] = lv;
}

// fallback monolithic attn
template<int SHG>
__global__ __launch_bounds__(256)
void attn_k(const float* __restrict__ sp_proj, const float* __restrict__ hgp,
            const float* __restrict__ w_h, const float* __restrict__ spatial,
            const float* __restrict__ h,
            short* __restrict__ a_hi, short* __restrict__ a_lo)
{
  const int b = blockIdx.x, half = blockIdx.y, tid = threadIdx.x;
  const int lane = tid & 63, wv = tid >> 6;
  __shared__ float hgs[KA_];
  __shared__ float whs[KA_];
  __shared__ float zs[L_];
  __shared__ float alph[L_];
  for (int i = tid; i < KA_; i += 256) {
    float s = 0.f;
#pragma unroll
    for (int sl = 0; sl < SHG; ++sl) s += hgp[((long)sl * B_ + b) * KA_ + i];
    hgs[i] = s; whs[i] = w_h[i];
  }
  __syncthreads();
  for (int l = wv; l < L_; l += 4) {
    const float* sp = sp_proj + ((long)b * L_ + l) * KA_;
    float s = 0.f;
    for (int k = lane; k < KA_; k += 64) s += whs[k] * tanhf(sp[k] + hgs[k]);
#pragma unroll
    for (int off = 32; off > 0; off >>= 1) s += __shfl_down(s, off);
    if (lane == 0) zs[l] = s;
  }
  __syncthreads();
  if (wv == 0) {
    float v = (lane < L_) ? zs[lane] : -INFINITY;
    float mx = v;
#pragma unroll
    for (int off = 32; off > 0; off >>= 1) mx = fmaxf(mx, __shfl_xor(mx, off));
    float e = (lane < L_) ? expf(v - mx) : 0.f;
    float sum = e;
#pragma unroll
    for (int off = 32; off > 0; off >>= 1) sum += __shfl_xor(sum, off);
    if (lane < L_) alph[lane] = e / sum;
  }
  __syncthreads();
  const int d4 = half * 256 + tid;
  const float4* h4 = (const float4*)h;
  const float4* sp4 = (const float4*)spatial;
  float4 acc = h4[(long)b * 512 + d4];
#pragma unroll 7
  for (int l = 0; l < L_; ++l) {
    const float w = alph[l];
    const float4 v = sp4[((long)b * L_ + l) * 512 + d4];
    acc.x = fmaf(w, v.x, acc.x); acc.y = fmaf(w, v.y, acc.y);
    acc.z = fmaf(w, v.z, acc.z); acc.w = fmaf(w, v.w, acc.w);
  }
  short4 hv, lv;
  split1(acc.x, &hv.x, &lv.x); split1(acc.y, &hv.y, &lv.y);
  split1(acc.z, &hv.z, &lv.z); split1(acc.w, &hv.w, &lv.w);
  *(short4*)&a_hi[(long)b * D_ + d4*4] = hv;
  *(short4*)&a_lo[(long)b * D_ + d4*4] = lv;
}

// ---- fused logits reduce + argmax + emb gather (ticket finalize) ----
// grid (B_, 8). Stripes are ordered disjoint ranges -> first-index tie rule
// preserved. Last-arriving block per b (device-scope ticket) finalizes.
template<int S>
__global__ __launch_bounds__(256)
void logits_am_k(const float* __restrict__ lp, const float* __restrict__ bias,
                 float* __restrict__ outL, float* __restrict__ cval,
                 int* __restrict__ cidx, int* __restrict__ ticket,
                 int* __restrict__ tok, float* __restrict__ tokout,
                 const float* __restrict__ embed,
                 short* __restrict__ xe_hi, short* __restrict__ xe_lo)
{
  const int b = blockIdx.x, s8 = blockIdx.y, tid = threadIdx.x;
  const int j0 = s8 * 1264;
  float bv = -INFINITY; int bi = 0x7fffffff;
  for (int j = j0 + tid; j < j0 + 1264; j += 256) {
    if (j < V_) {
      float v = bias[j];
#pragma unroll
      for (int sl = 0; sl < S; ++sl) v += lp[((long)sl * B_ + b) * VP_ + j];
      outL[(long)b * (T_*V_) + j] = v;
      if (v > bv) { bv = v; bi = j; }
    }
  }
  __shared__ float sv[256];
  __shared__ int   si[256];
  sv[tid] = bv; si[tid] = bi;
  __syncthreads();
  for (int s = 128; s > 0; s >>= 1) {
    if (tid < s) {
      const float ov = sv[tid + s]; const int oi = si[tid + s];
      if (ov > sv[tid] || (ov == sv[tid] && oi < si[tid])) { sv[tid] = ov; si[tid] = oi; }
    }
    __syncthreads();
  }
  __shared__ int lastf;
  if (tid == 0) {
    cval[b*8 + s8] = sv[0]; cidx[b*8 + s8] = si[0];
    __threadfence();                       // publish candidate (device scope)
    lastf = (atomicAdd(&ticket[b], 1) == 7);
  }
  __syncthreads();
  if (!lastf) return;
  __shared__ int stk;
  if (tid == 0) {
    __threadfence();                       // acquire
    float fv = cval[b*8]; int fi = cidx[b*8];
#pragma unroll
    for (int s = 1; s < 8; ++s) {
      const float v = cval[b*8 + s]; const int i = cidx[b*8 + s];
      if (v > fv || (v == fv && i < fi)) { fv = v; fi = i; }
    }
    tok[b] = fi; tokout[(long)b * T_] = (float)fi; stk = fi;
  }
  __syncthreads();
  const float* e = embed + (long)stk * E_;
  for (int i = tid; i < E_; i += 256)
    split1(e[i], &xe_hi[(long)b*E_ + i], &xe_lo[(long)b*E_ + i]);
}

// fallback monolithic logits+argmax
template<int S>
__global__ __launch_bounds__(256)
void logits_argmax_k(const float* __restrict__ lp, const float* __restrict__ bias,
                     float* __restrict__ outL, int* __restrict__ tok,
                     float* __restrict__ tokout)
{
  const int b = blockIdx.x, tid = threadIdx.x;
  float bv = -INFINITY; int bi = 0x7fffffff;
  for (int j = tid; j < V_; j += 256) {
    float v = bias[j];
#pragma unroll
    for (int sl = 0; sl < S; ++sl) v += lp[((long)sl * B_ + b) * VP_ + j];
    outL[(long)b * (T_*V_) + j] = v;
    if (v > bv) { bv = v; bi = j; }
  }
  __shared__ float sv[256];
  __shared__ int   si[256];
  sv[tid] = bv; si[tid] = bi;
  __syncthreads();
  for (int s = 128; s > 0; s >>= 1) {
    if (tid < s) {
      const float ov = sv[tid + s]; const int oi = si[tid + s];
      if (ov > sv[tid] || (ov == sv[tid] && oi < si[tid])) { sv[tid] = ov; si[tid] = oi; }
    }
    __syncthreads();
  }
  if (tid == 0) { tok[b] = si[0]; tokout[(long)b * T_] = (float)si[0]; }
}

// ============ host ============
extern "C" void kernel_launch(void* const* d_in, const int* in_sizes, int n_in,
                              void* d_out, int out_size, void* d_ws, size_t ws_size,
                              hipStream_t stream)
{
  const float* spatial  = (const float*)d_in[0];
  const float* global_  = (const float*)d_in[1];
  const float* embed    = (const float*)d_in[2];
  const float* W_ih     = (const float*)d_in[3];
  const float* W_hh     = (const float*)d_in[4];
  const float* b_ih     = (const float*)d_in[5];
  const float* b_hh     = (const float*)d_in[6];
  const float* W_v      = (const float*)d_in[7];
  const float* W_g      = (const float*)d_in[8];
  const float* w_h      = (const float*)d_in[9];
  const float* W_p_w    = (const float*)d_in[10];
  const float* W_p_b    = (const float*)d_in[11];
  const float* W_init_h = (const float*)d_in[12];
  const float* W_init_m = (const float*)d_in[13];
  float* out = (float*)d_out;
  float* tokout = out + (long)B_ * T_ * V_;

  char* base = (char*)d_ws;
  const size_t NEED_PRE = 284983808;
  const size_t NEED_FB  = 62390784;
  if (ws_size < NEED_FB) return;

  if (ws_size >= NEED_PRE) {
    float* sp      = (float*)(base + 0);           // 12,845,056
    float* h       = (float*)(base + 12845056);    //  1,048,576
    float* m       = (float*)(base + 13893632);    //  1,048,576
    short* h_hi    = (short*)(base + 14942208);    //    524,288
    short* h_lo    = (short*)(base + 15466496);
    short* a_hi    = (short*)(base + 15990784);
    short* a_lo    = (short*)(base + 16515072);
    short* xe_hi   = (short*)(base + 17039360);    //    131,072
    short* xe_lo   = (short*)(base + 17170432);
    short* g_hi    = (short*)(base + 18350080);    //    524,288
    short* g_lo    = (short*)(base + 18874368);
    float* gconst  = (float*)(base + 19398656);    //  4,194,304
    int*   tok     = (int*)  (base + 23592960);    //        512
    float* arena   = (float*)(base + 23593472);    // 83,886,080
    short* Wcat_hi = (short*)(base + 107479552);   // 41,943,040 (8192 x 2560)
    short* Wcat_lo = (short*)(base + 149422592);
    short* Wp_hi   = (short*)(base + 191365632);   // 41,418,752 (10112 x 2048)
    short* Wp_lo   = (short*)(base + 232784384);
    short* WvT_hi  = (short*)(base + 274203136);   //  2,097,152
    short* WvT_lo  = (short*)(base + 276300288);
    short* WgT_hi  = (short*)(base + 278397440);
    short* WgT_lo  = (short*)(base + 280494592);
    float* cval    = (float*)(base + 282591744);   //      4,096
    int*   cidx    = (int*)  (base + 282595840);   //      4,096
    int*   tickets = (int*)  (base + 282599936);   //     10,240 (T x B)

    init_k<<<10, 256, 0, stream>>>(tok, tickets);
    split_plane_k<<<256, 256, 0, stream>>>(global_, (long)B_*D_, g_hi, g_lo);

    // ---- sp = spatial @ W_v (gemm_lds S=4, k_len=512) ----
    split_t_k<<<dim3(KA_/64, D_/64), 256, 0, stream>>>(W_v, D_, KA_, WvT_hi, WvT_lo);
    short* spA_hi = Wp_hi;
    short* spA_lo = (short*)((char*)Wp_hi + 25690112);
    split_plane_k<<<12544, 256, 0, stream>>>(spatial, (long)B_*L_*D_, spA_hi, spA_lo);
    float* sppart = (float*)Wcat_hi;
    gemm_lds<<<dim3(4, 4, 49), 256, 0, stream>>>(
        spA_hi, spA_lo, D_, spA_hi, spA_lo, D_, 1<<30,
        WvT_hi, WvT_lo, D_, sppart, B_*L_, KA_, 512);
    reduce_sp_k<4><<<3136, 256, 0, stream>>>((const float4*)sppart, (float4*)sp);

    // ---- gconst = global_ @ W_ih[:,512:]^T + b_ih + b_hh (gemm_lds S=8) ----
    short* Wglob_hi = Wp_hi;
    short* Wglob_lo = (short*)((char*)Wp_hi + 33554432);
    split_nt_k<<<dim3(2, H4_), 256, 0, stream>>>(W_ih + 512, ED_, H4_, D_, Wglob_hi, Wglob_lo, D_, 0);
    gemm_lds<<<dim3(64, 8, 1), 256, 0, stream>>>(
        g_hi, g_lo, D_, g_hi, g_lo, D_, 1<<30,
        Wglob_hi, Wglob_lo, D_, arena, B_, H4_, 256);
    gred_k<8><<<(B_*H4_)/256, 256, 0, stream>>>(arena, b_ih, b_hh, gconst);

    // ---- loop weight planes ----
    split_nt_k<<<dim3(1, H4_), 256, 0, stream>>>(W_ih, ED_, H4_, E_, Wcat_hi, Wcat_lo, KT2_, 0);
    split_nt_k<<<dim3(2, H4_), 256, 0, stream>>>(W_hh, H_, H4_, H_, Wcat_hi, Wcat_lo, KT2_, E_);
    split_nt_k<<<dim3(2, VP_), 256, 0, stream>>>(W_p_w, H_, V_, H_, Wp_hi, Wp_lo, H_, 0);
    split_t_k<<<dim3(KA_/64, H_/64), 256, 0, stream>>>(W_g, H_, KA_, WgT_hi, WgT_lo);

    // ---- h0/m0 combined: WT = [W_init_h^T ; W_init_m^T] (4096 x 2048) ----
    {
      short* WTh = (short*)arena;                          // 16,777,216 B
      short* WTl = (short*)((char*)arena + 16777216);      // 16,777,216 B
      float* prt = (float*)((char*)arena + 33554432);      // 8 x 128 x 4096 x 4
      split_t_k<<<dim3(H_/64, D_/64), 256, 0, stream>>>(W_init_h, D_, H_, WTh, WTl);
      split_t_k<<<dim3(H_/64, D_/64), 256, 0, stream>>>(
          W_init_m, D_, H_, WTh + (long)H_*D_, WTl + (long)H_*D_);
      gemm_lds<<<dim3(32, 8, 1), 256, 0, stream>>>(
          g_hi, g_lo, D_, g_hi, g_lo, D_, 1<<30,
          WTh, WTl, D_, prt, B_, 4096, 256);
      init_hm_reduce_k<8><<<(B_*4096)/256, 256, 0, stream>>>(prt, h, m, h_hi, h_lo);
    }

    gather_emb_k<<<B_, 256, 0, stream>>>(embed, tok, xe_hi, xe_lo);

    for (int t = 0; t < T_; ++t) {
      // gates: A = [emb(512) | h(2048)], S=8, k_len=320
      gemm_lds<<<dim3(64, 8, 1), 256, 0, stream>>>(
          xe_hi, xe_lo, E_, h_hi, h_lo, H_, E_,
          Wcat_hi, Wcat_lo, KT2_, arena, B_, H4_, 320);
      lstm_reduce_k<8><<<(B_*H_)/256, 256, 0, stream>>>(
          arena, gconst, nullptr, nullptr, h, m, h_hi, h_lo);
      // hg: S=32, k_len=64
      gemm_lds<<<dim3(4, 32, 1), 256, 0, stream>>>(
          h_hi, h_lo, H_, h_hi, h_lo, H_, 1<<30,
          WgT_hi, WgT_lo, H_, arena, B_, KA_, 64);
      attn_one<<<dim3(B_, 2), 256, 0, stream>>>(arena, sp, w_h, spatial, h, a_hi, a_lo);
      // logits: S=8, k_len=256
      gemm_lds<<<dim3(79, 8, 1), 256, 0, stream>>>(
          a_hi, a_lo, H_, a_hi, a_lo, H_, 1<<30,
          Wp_hi, Wp_lo, H_, arena, B_, VP_, 256);
      // fused reduce + argmax + emb gather (ticket finalize)
      logits_am_k<8><<<dim3(B_, 8), 256, 0, stream>>>(
          arena, W_p_b, out + (long)t * V_, cval, cidx, tickets + t*B_,
          tok, tokout + t, embed, xe_hi, xe_lo);
    }
  } else {
    // -------- fallback: fp32 weights, on-the-fly split --------
    float* sp    = (float*)(base + 0);
    float* WvTf  = (float*)(base + 12845056);
    float* WgTf  = (float*)(base + 17039360);
    float* h     = (float*)(base + 21233664);
    float* m     = (float*)(base + 22282240);
    short* h_hi  = (short*)(base + 24379392);
    short* h_lo  = (short*)(base + 24903680);
    short* a_hi  = (short*)(base + 25427968);
    short* a_lo  = (short*)(base + 25952256);
    short* xh_hi = (short*)(base + 26476544);
    short* xh_lo = (short*)(base + 27656192);
    int*   tok   = (int*)  (base + 28835840);
    float* arena = (float*)(base + 28836352);

    init_k<<<10, 256, 0, stream>>>(tok, tok); // tickets unused in fallback
    transpose_f32<<<dim3(KA_/64, D_/64), 256, 0, stream>>>(W_v, D_, KA_, WvTf);
    gemm_mfma<true><<<dim3(4, 1, 49), 256, 0, stream>>>(
        spatial, nullptr, D_, WvTf, D_, nullptr, 0, 1<<30, sp, B_*L_, KA_, KA_, D_);
    transpose_f32<<<dim3(KA_/64, H_/64), 256, 0, stream>>>(W_g, H_, KA_, WgTf);
    {
      float* WT  = arena;
      float* prt = (float*)((char*)arena + 16777216);
      transpose_f32<<<dim3(H_/64, D_/64), 256, 0, stream>>>(W_init_h, D_, H_, WT);
      gemm_mfma<true><<<dim3(16, 4, 1), 256, 0, stream>>>(
          global_, nullptr, D_, WT, D_, nullptr, 0, 1<<30, prt, B_, H_, H_, 512);
      reduce_tanh_k<4><<<(B_*H_)/256, 256, 0, stream>>>(prt, h, h_hi, h_lo);
      transpose_f32<<<dim3(H_/64, D_/64), 256, 0, stream>>>(W_init_m, D_, H_, WT);
      gemm_mfma<true><<<dim3(16, 4, 1), 256, 0, stream>>>(
          global_, nullptr, D_, WT, D_, nullptr, 0, 1<<30, prt, B_, H_, H_, 512);
      reduce_tanh_k<4><<<(B_*H_)/256, 256, 0, stream>>>(prt, m, nullptr, nullptr);
    }
    for (int t = 0; t < T_; ++t) {
      gather_xh_k<<<B_, 256, 0, stream>>>(embed, global_, h_hi, h_lo, tok, xh_hi, xh_lo);
      gemm_mfma<false><<<dim3(64, 8, 1), 256, 0, stream>>>(
          xh_hi, xh_lo, KT_, W_ih, ED_, W_hh, H_, ED_, arena, B_, H4_, H4_, 576);
      lstm_reduce_k<8><<<(B_*H_)/256, 256, 0, stream>>>(
          arena, nullptr, b_ih, b_hh, h, m, h_hi, h_lo);
      gemm_mfma<false><<<dim3(4, 16, 1), 256, 0, stream>>>(
          h_hi, h_lo, H_, WgTf, H_, nullptr, 0, 1<<30, arena, B_, KA_, KA_, 128);
      attn_k<16><<<dim3(B_, 2), 256, 0, stream>>>(sp, arena, w_h, spatial, h, a_hi, a_lo);
      gemm_mfma<false><<<dim3(79, 4, 1), 256, 0, stream>>>(
          a_hi, a_lo, H_, W_p_w, H_, nullptr, 0, 1<<30, arena, B_, VP_, V_, 512);
      logits_argmax_k<4><<<B_, 256, 0, stream>>>(
          arena, W_p_b, out + (long)t * V_, tok, tokout + t);
    }
  }
}

// Round 15
// 2587.608 us; speedup vs baseline: 1.1380x; 1.1380x over previous
//
#include <hip/hip_runtime.h>
#include <math.h>

// Model_13348758356240 — R15: revert to R12 (measured best, 2593us).
// gemm_lds split-K engine everywhere, attn_one fusion, parallel logits
// reduce/argmax as two small kernels (logits_part_k + argmax_fin_k).

typedef __attribute__((ext_vector_type(8))) short bf16x8;
typedef __attribute__((ext_vector_type(4))) float f32x4;

#define B_ 128
#define L_ 49
#define D_ 2048
#define H_ 2048
#define E_ 512
#define KA_ 512
#define V_ 10000
#define T_ 20
#define ED_ 2560
#define KT_ 4608
#define KT2_ 2560
#define H4_ 8192
#define VP_ 10112

__device__ __forceinline__ void split1(float x, short* hi, short* lo){
  unsigned u = __float_as_uint(x);
  *hi = (short)(u >> 16);
  float r = x - __uint_as_float(u & 0xffff0000u);
  *lo = (short)(__float_as_uint(r) >> 16);
}
__device__ __forceinline__ void split8(float4 a, float4 b, bf16x8& h, bf16x8& l){
  float xs[8] = {a.x,a.y,a.z,a.w,b.x,b.y,b.z,b.w};
#pragma unroll
  for (int i=0;i<8;++i){
    unsigned u = __float_as_uint(xs[i]);
    h[i] = (short)(u>>16);
    float r = xs[i] - __uint_as_float(u & 0xffff0000u);
    l[i] = (short)(__float_as_uint(r)>>16);
  }
}

#define MFMA16(d,a,b,c) d = __builtin_amdgcn_mfma_f32_16x16x32_bf16(a,b,c,0,0,0)

__device__ __forceinline__ void gl_lds16(const short* g, char* l){
  __builtin_amdgcn_global_load_lds(
      (const __attribute__((address_space(1))) unsigned int*)g,
      (__attribute__((address_space(3))) unsigned int*)l, 16, 0, 0);
}

// ============ R8-proven GEMM: single-buffer LDS staging, dual-A sources ============
// A from A1 (k < ksplit, lda1) or A2 (k >= ksplit, lda2); W planes [Np][ldw].
// Block 256 thr / 4 waves; tile 128Mx128Nx64K; LDS 64KB. k_len % 64 == 0.
// ksplit must be a multiple of 64.
__global__ __launch_bounds__(256)
void gemm_lds(const short* __restrict__ A1h, const short* __restrict__ A1l, int lda1,
              const short* __restrict__ A2h, const short* __restrict__ A2l, int lda2,
              int ksplit,
              const short* __restrict__ Wh, const short* __restrict__ Wl, int ldw,
              float* __restrict__ Cp, int Mtot, int Np, int k_len)
{
  __shared__ __align__(16) char smem[65536];
  const int tid = threadIdx.x;
  const int wid = tid >> 6, lane = tid & 63;
  const int lr = lane & 15, lg = lane >> 4;
  const int m0 = blockIdx.z * 128;
  const int nblk = blockIdx.x * 128;
  const int kb0 = blockIdx.y * k_len;

  const int li8 = lane >> 3;
  const int kx  = 8 * ((lane & 7) ^ li8);

  f32x4 acc[8][2];
#pragma unroll
  for (int i=0;i<8;++i)
#pragma unroll
    for (int r=0;r<4;++r){ acc[i][0][r]=0.f; acc[i][1][r]=0.f; }

  const int rA = wid*32 + lr, rB = rA + 16;
  const int sw7 = lr & 7;

  for (int kt = 0; kt < k_len; kt += 64) {
    const int kb = kb0 + kt;
    if (wid == 0) {
#pragma unroll
      for (int j = 0; j < 16; ++j)
        gl_lds16(Wh + (long)(nblk + j*8 + li8)*ldw + kb + kx, smem + j*1024);
    } else if (wid == 1) {
#pragma unroll
      for (int j = 0; j < 16; ++j)
        gl_lds16(Wl + (long)(nblk + j*8 + li8)*ldw + kb + kx, smem + 16384 + j*1024);
    } else {
      const short *Ph, *Pl; int ldx, kc;
      if (kb < ksplit) { Ph = A1h; Pl = A1l; ldx = lda1; kc = kb; }
      else             { Ph = A2h; Pl = A2l; ldx = lda2; kc = kb - ksplit; }
      if (wid == 2) {
#pragma unroll
        for (int j = 0; j < 16; ++j)
          gl_lds16(Ph + (long)(m0 + j*8 + li8)*ldx + kc + kx, smem + 32768 + j*1024);
      } else {
#pragma unroll
        for (int j = 0; j < 16; ++j)
          gl_lds16(Pl + (long)(m0 + j*8 + li8)*ldx + kc + kx, smem + 49152 + j*1024);
      }
    }
    asm volatile("s_waitcnt vmcnt(0)");
    __syncthreads();

#pragma unroll
    for (int h = 0; h < 2; ++h) {
      const int c16 = (h<<2) + lg;
      const int swz = (c16 ^ sw7) << 4;
      const bf16x8 whA = *(const bf16x8*)(smem +         rA*128 + swz);
      const bf16x8 wlA = *(const bf16x8*)(smem + 16384 + rA*128 + swz);
      const bf16x8 whB = *(const bf16x8*)(smem +         rB*128 + swz);
      const bf16x8 wlB = *(const bf16x8*)(smem + 16384 + rB*128 + swz);
#pragma unroll
      for (int mt = 0; mt < 8; ++mt) {
        const int aoff = (mt*16 + lr)*128 + swz;
        const bf16x8 ah = *(const bf16x8*)(smem + 32768 + aoff);
        const bf16x8 al = *(const bf16x8*)(smem + 49152 + aoff);
        MFMA16(acc[mt][0], ah, whA, acc[mt][0]);
        MFMA16(acc[mt][1], ah, whB, acc[mt][1]);
        MFMA16(acc[mt][0], ah, wlA, acc[mt][0]);
        MFMA16(acc[mt][1], ah, wlB, acc[mt][1]);
        MFMA16(acc[mt][0], al, whA, acc[mt][0]);
        MFMA16(acc[mt][1], al, whB, acc[mt][1]);
      }
    }
    __syncthreads();
  }

  const long srow = (long)blockIdx.y * Mtot + m0;
#pragma unroll
  for (int mt=0; mt<8; ++mt)
#pragma unroll
    for (int nt=0; nt<2; ++nt){
      const int col = nblk + wid*32 + nt*16 + lr;
#pragma unroll
      for (int r=0; r<4; ++r)
        Cp[(srow + mt*16 + 4*lg + r)*Np + col] = acc[mt][nt][r];
    }
}

// ============ double-buffered GEMM (kept for reference/unused) ============
__global__ __launch_bounds__(256)
void gemm_db(const short* __restrict__ A1h, const short* __restrict__ A1l, int lda1,
             const short* __restrict__ A2h, const short* __restrict__ A2l, int lda2,
             int ksplit,
             const short* __restrict__ Wh, const short* __restrict__ Wl, int ldw,
             float* __restrict__ Cp, int Mtot, int Np, int k_len)
{
  __shared__ __align__(16) char smem[131072];
  const int tid = threadIdx.x;
  const int wid = tid >> 6, lane = tid & 63;
  const int lr = lane & 15, lg = lane >> 4;
  const int m0 = blockIdx.z * 128;
  const int nblk = blockIdx.x * 128;
  const int kb0 = blockIdx.y * k_len;

  const int li8 = lane >> 3;
  const int kx  = 8 * ((lane & 7) ^ li8);

  f32x4 acc[8][2];
#pragma unroll
  for (int i=0;i<8;++i)
#pragma unroll
    for (int r=0;r<4;++r){ acc[i][0][r]=0.f; acc[i][1][r]=0.f; }

  const int rA = wid*32 + lr, rB = rA + 16;
  const int sw7 = lr & 7;

  auto STAGE = [&](int kb, int buf) {
    char* s = smem + buf*65536;
    if (wid == 0) {
#pragma unroll
      for (int j = 0; j < 16; ++j)
        gl_lds16(Wh + (long)(nblk + j*8 + li8)*ldw + kb + kx, s + j*1024);
    } else if (wid == 1) {
#pragma unroll
      for (int j = 0; j < 16; ++j)
        gl_lds16(Wl + (long)(nblk + j*8 + li8)*ldw + kb + kx, s + 16384 + j*1024);
    } else {
      const short *Ph, *Pl; int ldx, kc;
      if (kb < ksplit) { Ph = A1h; Pl = A1l; ldx = lda1; kc = kb; }
      else             { Ph = A2h; Pl = A2l; ldx = lda2; kc = kb - ksplit; }
      if (wid == 2) {
#pragma unroll
        for (int j = 0; j < 16; ++j)
          gl_lds16(Ph + (long)(m0 + j*8 + li8)*ldx + kc + kx, s + 32768 + j*1024);
      } else {
#pragma unroll
        for (int j = 0; j < 16; ++j)
          gl_lds16(Pl + (long)(m0 + j*8 + li8)*ldx + kc + kx, s + 49152 + j*1024);
      }
    }
  };

  auto COMPUTE = [&](int buf) {
    char* s = smem + buf*65536;
#pragma unroll
    for (int h = 0; h < 2; ++h) {
      const int c16 = (h<<2) + lg;
      const int swz = (c16 ^ sw7) << 4;
      const bf16x8 whA = *(const bf16x8*)(s +         rA*128 + swz);
      const bf16x8 wlA = *(const bf16x8*)(s + 16384 + rA*128 + swz);
      const bf16x8 whB = *(const bf16x8*)(s +         rB*128 + swz);
      const bf16x8 wlB = *(const bf16x8*)(s + 16384 + rB*128 + swz);
#pragma unroll
      for (int mt = 0; mt < 8; ++mt) {
        const int aoff = (mt*16 + lr)*128 + swz;
        const bf16x8 ah = *(const bf16x8*)(s + 32768 + aoff);
        const bf16x8 al = *(const bf16x8*)(s + 49152 + aoff);
        MFMA16(acc[mt][0], ah, whA, acc[mt][0]);
        MFMA16(acc[mt][1], ah, whB, acc[mt][1]);
        MFMA16(acc[mt][0], ah, wlA, acc[mt][0]);
        MFMA16(acc[mt][1], ah, wlB, acc[mt][1]);
        MFMA16(acc[mt][0], al, whA, acc[mt][0]);
        MFMA16(acc[mt][1], al, whB, acc[mt][1]);
      }
    }
  };

  STAGE(kb0, 0);
  asm volatile("s_waitcnt vmcnt(0)");
  __syncthreads();
  int cur = 0;
  for (int kt = 64; kt < k_len; kt += 64) {
    STAGE(kb0 + kt, cur ^ 1);
    COMPUTE(cur);
    asm volatile("s_waitcnt vmcnt(0)");
    __syncthreads();
    cur ^= 1;
  }
  COMPUTE(cur);

  const long srow = (long)blockIdx.y * Mtot + m0;
#pragma unroll
  for (int mt=0; mt<8; ++mt)
#pragma unroll
    for (int nt=0; nt<2; ++nt){
      const int col = nblk + wid*32 + nt*16 + lr;
#pragma unroll
      for (int r=0; r<4; ++r)
        Cp[(srow + mt*16 + 4*lg + r)*Np + col] = acc[mt][nt][r];
    }
}

// ============ fallback GEMM: fp32 W, on-the-fly split ============
template<bool AF32>
__global__ __launch_bounds__(256)
void gemm_mfma(const void* Ahv, const void* Alv, int lda,
               const float* __restrict__ W1, int ldw1,
               const float* __restrict__ W2, int ldw2, int ksplit,
               float* __restrict__ Cp, int Mtot, int Np, int Nvalid, int k_len)
{
  const int tid = threadIdx.x;
  const int wid = tid >> 6, lane = tid & 63;
  const int lr = lane & 15, lg = lane >> 4;
  const int m0 = blockIdx.z * 128;
  const int nw = blockIdx.x * 128 + wid * 32;
  const int kb = blockIdx.y * k_len;

  int rowA = nw + lr;       if (rowA >= Nvalid) rowA = Nvalid - 1;
  int rowB = nw + 16 + lr;  if (rowB >= Nvalid) rowB = Nvalid - 1;

  f32x4 acc[8][2];
#pragma unroll
  for (int i=0;i<8;++i)
#pragma unroll
    for (int r=0;r<4;++r){ acc[i][0][r]=0.f; acc[i][1][r]=0.f; }

  for (int kk = 0; kk < k_len; kk += 32) {
    const int kg = kb + kk;
    const float *pA, *pB;
    if (W2 && kg >= ksplit) {
      pA = W2 + (long)rowA*ldw2 + (kg - ksplit) + 8*lg;
      pB = W2 + (long)rowB*ldw2 + (kg - ksplit) + 8*lg;
    } else {
      pA = W1 + (long)rowA*ldw1 + kg + 8*lg;
      pB = W1 + (long)rowB*ldw1 + kg + 8*lg;
    }
    bf16x8 whA, wlA, whB, wlB;
    split8(*(const float4*)pA, *(const float4*)(pA+4), whA, wlA);
    split8(*(const float4*)pB, *(const float4*)(pB+4), whB, wlB);

    bf16x8 ah[8], al[8];
    if constexpr (AF32) {
      const float* Af = (const float*)Ahv;
#pragma unroll
      for (int mt=0; mt<8; ++mt){
        const float* ap = Af + (long)(m0 + mt*16 + lr)*lda + kg + 8*lg;
        split8(*(const float4*)ap, *(const float4*)(ap+4), ah[mt], al[mt]);
      }
    } else {
      const short* Ah = (const short*)Ahv;
      const short* Al = (const short*)Alv;
#pragma unroll
      for (int mt=0; mt<8; ++mt){
        const long off = (long)(m0 + mt*16 + lr)*lda + kg + 8*lg;
        ah[mt] = *(const bf16x8*)(Ah + off);
        al[mt] = *(const bf16x8*)(Al + off);
      }
    }
#pragma unroll
    for (int mt=0; mt<8; ++mt){
      MFMA16(acc[mt][0], ah[mt], whA, acc[mt][0]);
      MFMA16(acc[mt][1], ah[mt], whB, acc[mt][1]);
      MFMA16(acc[mt][0], ah[mt], wlA, acc[mt][0]);
      MFMA16(acc[mt][1], ah[mt], wlB, acc[mt][1]);
      MFMA16(acc[mt][0], al[mt], whA, acc[mt][0]);
      MFMA16(acc[mt][1], al[mt], whB, acc[mt][1]);
    }
  }

  const long srow = (long)blockIdx.y * Mtot + m0;
#pragma unroll
  for (int mt=0; mt<8; ++mt)
#pragma unroll
    for (int nt=0; nt<2; ++nt){
      const int col = nw + nt*16 + lr;
#pragma unroll
      for (int r=0; r<4; ++r)
        Cp[(srow + mt*16 + 4*lg + r)*Np + col] = acc[mt][nt][r];
    }
}

// ============ prep kernels ============
__global__ __launch_bounds__(256)
void split_nt_k(const float* __restrict__ W, int src_ld, int Nv, int kcount,
                short* __restrict__ Wh, short* __restrict__ Wl, int ldo, int ko)
{
  const int n = blockIdx.y;
  const int k = blockIdx.x * 1024 + threadIdx.x * 4;
  if (k >= kcount) return;
  short4 hv, lv;
  if (n < Nv) {
    const float4 v = *(const float4*)&W[(long)n*src_ld + k];
    split1(v.x, &hv.x, &lv.x); split1(v.y, &hv.y, &lv.y);
    split1(v.z, &hv.z, &lv.z); split1(v.w, &hv.w, &lv.w);
  } else {
    hv.x=hv.y=hv.z=hv.w=0; lv.x=lv.y=lv.z=lv.w=0;
  }
  *(short4*)&Wh[(long)n*ldo + ko + k] = hv;
  *(short4*)&Wl[(long)n*ldo + ko + k] = lv;
}

__global__ __launch_bounds__(256)
void split_t_k(const float* __restrict__ in, int K, int N,
               short* __restrict__ Oh, short* __restrict__ Ol)
{
  __shared__ float t[64][65];
  const int tid = threadIdx.x;
  const int c0 = blockIdx.x * 64, r0 = blockIdx.y * 64;
  const int lx = tid & 63, ly = tid >> 6;
#pragma unroll
  for (int i = 0; i < 16; ++i)
    t[ly + 4*i][lx] = in[(long)(r0 + ly + 4*i) * N + c0 + lx];
  __syncthreads();
#pragma unroll
  for (int i = 0; i < 16; ++i) {
    short hh, ll;
    split1(t[lx][ly + 4*i], &hh, &ll);
    const long o = (long)(c0 + ly + 4*i) * K + r0 + lx;
    Oh[o] = hh; Ol[o] = ll;
  }
}

__global__ __launch_bounds__(256)
void split_plane_k(const float* __restrict__ in, long n,
                   short* __restrict__ oh, short* __restrict__ ol)
{
  const long i = ((long)blockIdx.x * 256 + threadIdx.x) * 4;
  if (i >= n) return;
  const float4 v = *(const float4*)&in[i];
  short4 hv, lv;
  split1(v.x, &hv.x, &lv.x); split1(v.y, &hv.y, &lv.y);
  split1(v.z, &hv.z, &lv.z); split1(v.w, &hv.w, &lv.w);
  *(short4*)&oh[i] = hv;
  *(short4*)&ol[i] = lv;
}

__global__ __launch_bounds__(256)
void transpose_f32(const float* __restrict__ in, int R, int C, float* __restrict__ out)
{
  __shared__ float t[64][65];
  const int tid = threadIdx.x;
  const int c0 = blockIdx.x * 64, r0 = blockIdx.y * 64;
  const int lx = tid & 63, ly = tid >> 6;
#pragma unroll
  for (int i = 0; i < 16; ++i)
    t[ly + 4*i][lx] = in[(long)(r0 + ly + 4*i) * C + c0 + lx];
  __syncthreads();
#pragma unroll
  for (int i = 0; i < 16; ++i)
    out[(long)(c0 + ly + 4*i) * R + r0 + lx] = t[lx][ly + 4*i];
}

template<int S>
__global__ void reduce_sp_k(const float4* __restrict__ p, float4* __restrict__ sp)
{
  const long i = (long)blockIdx.x * 256 + threadIdx.x;
  const long s = 802816;
  float4 r; r.x = 0.f; r.y = 0.f; r.z = 0.f; r.w = 0.f;
#pragma unroll
  for (int sl = 0; sl < S; ++sl) {
    const float4 v = p[i + sl*s];
    r.x += v.x; r.y += v.y; r.z += v.z; r.w += v.w;
  }
  sp[i] = r;
}

template<int S>
__global__ __launch_bounds__(256)
void gred_k(const float* __restrict__ prt, const float* __restrict__ b_ih,
            const float* __restrict__ b_hh, float* __restrict__ gconst)
{
  const int idx = blockIdx.x * 256 + threadIdx.x;
  const int n = idx & (H4_ - 1);
  float s = b_ih[n] + b_hh[n];
#pragma unroll
  for (int sl = 0; sl < S; ++sl) s += prt[(long)sl * (B_*H4_) + idx];
  gconst[idx] = s;
}

// ============ step kernels ============
__global__ void init_tok_k(int* tok) {
  if (threadIdx.x < B_) tok[threadIdx.x] = 1; // START_IDX
}

__global__ __launch_bounds__(256)
void reduce_tanh_k(const float* __restrict__ gp, int S, float* __restrict__ out,
                   short* __restrict__ ohi, short* __restrict__ olo)
{
  const int idx = blockIdx.x * 256 + threadIdx.x;
  float s = 0.f;
  for (int sl = 0; sl < S; ++sl) s += gp[(long)sl * (B_*H_) + idx];
  s = tanhf(s);
  out[idx] = s;
  if (ohi) split1(s, &ohi[idx], &olo[idx]);
}

__global__ void gather_emb_k(const float* __restrict__ embed, const int* __restrict__ tok,
                             short* __restrict__ xe_hi, short* __restrict__ xe_lo)
{
  const int b = blockIdx.x, tid = threadIdx.x;
  const int tk = tok[b];
  const float* e = embed + (long)tk * E_;
  for (int i = tid; i < E_; i += 256) split1(e[i], &xe_hi[(long)b*E_ + i], &xe_lo[(long)b*E_ + i]);
}

__global__ void gather_xh_k(const float* __restrict__ embed, const float* __restrict__ global_,
                            const short* __restrict__ h_hi, const short* __restrict__ h_lo,
                            const int* __restrict__ tok,
                            short* __restrict__ xh_hi, short* __restrict__ xh_lo)
{
  const int b = blockIdx.x, tid = threadIdx.x;
  const int tk = tok[b];
  short* rh = xh_hi + (long)b * KT_;
  short* rl = xh_lo + (long)b * KT_;
  const float* e = embed + (long)tk * E_;
  for (int i = tid; i < E_; i += 256) split1(e[i], &rh[i], &rl[i]);
  for (int i = tid; i < D_; i += 256) split1(global_[(long)b * D_ + i], &rh[E_ + i], &rl[E_ + i]);
  for (int i = tid; i < H_; i += 256) { rh[ED_ + i] = h_hi[(long)b * H_ + i]; rl[ED_ + i] = h_lo[(long)b * H_ + i]; }
}

template<int S>
__global__ __launch_bounds__(256)
void lstm_reduce_k(const float* __restrict__ gp, const float* __restrict__ gconst,
                   const float* __restrict__ b1, const float* __restrict__ b2,
                   float* __restrict__ h, float* __restrict__ m,
                   short* __restrict__ h_hi, short* __restrict__ h_lo)
{
  const int idx = blockIdx.x * 256 + threadIdx.x;
  const int b = idx >> 11, n = idx & (H_ - 1);
  float g[4];
#pragma unroll
  for (int j = 0; j < 4; ++j) {
    float s = gconst ? gconst[(long)b * H4_ + j*H_ + n] : (b1[j*H_ + n] + b2[j*H_ + n]);
#pragma unroll
    for (int sl = 0; sl < S; ++sl) s += gp[((long)sl * B_ + b) * H4_ + j*H_ + n];
    g[j] = s;
  }
  const float si = 1.f / (1.f + expf(-g[0]));
  const float sf = 1.f / (1.f + expf(-g[1]));
  const float gg = tanhf(g[2]);
  const float so = 1.f / (1.f + expf(-g[3]));
  const float mn = sf * m[idx] + si * gg;
  const float hn = so * tanhf(mn);
  m[idx] = mn; h[idx] = hn;
  split1(hn, &h_hi[idx], &h_lo[idx]);
}

// fused attention: hg-reduce + z + softmax + c + comb. grid (B_, 2).
__global__ __launch_bounds__(256)
void attn_one(const float* __restrict__ hgp, const float* __restrict__ sp,
              const float* __restrict__ w_h, const float* __restrict__ spatial,
              const float* __restrict__ h,
              short* __restrict__ a_hi, short* __restrict__ a_lo)
{
  const int b = blockIdx.x, dh = blockIdx.y, tid = threadIdx.x;
  const int wv = tid >> 6, lane = tid & 63;
  __shared__ float hgs[KA_];
  __shared__ float whs[KA_];
  __shared__ float zs[L_];
  __shared__ float alph[L_];
  for (int i = tid; i < KA_; i += 256) {
    float s = 0.f;
#pragma unroll
    for (int sl = 0; sl < 32; ++sl) s += hgp[((long)sl * B_ + b) * KA_ + i];
    hgs[i] = s; whs[i] = w_h[i];
  }
  __syncthreads();
  const int k0 = lane * 8;
  for (int l = wv; l < L_; l += 4) {
    const float4* spv = (const float4*)(sp + ((long)b * L_ + l) * KA_ + k0);
    const float4 s1 = spv[0], s2 = spv[1];
    float s = whs[k0]   * tanhf(s1.x + hgs[k0])
            + whs[k0+1] * tanhf(s1.y + hgs[k0+1])
            + whs[k0+2] * tanhf(s1.z + hgs[k0+2])
            + whs[k0+3] * tanhf(s1.w + hgs[k0+3])
            + whs[k0+4] * tanhf(s2.x + hgs[k0+4])
            + whs[k0+5] * tanhf(s2.y + hgs[k0+5])
            + whs[k0+6] * tanhf(s2.z + hgs[k0+6])
            + whs[k0+7] * tanhf(s2.w + hgs[k0+7]);
#pragma unroll
    for (int off = 32; off > 0; off >>= 1) s += __shfl_down(s, off);
    if (lane == 0) zs[l] = s;
  }
  __syncthreads();
  if (wv == 0) {
    float v = (lane < L_) ? zs[lane] : -INFINITY;
    float mx = v;
#pragma unroll
    for (int off = 32; off > 0; off >>= 1) mx = fmaxf(mx, __shfl_xor(mx, off));
    float e = (lane < L_) ? expf(v - mx) : 0.f;
    float sum = e;
#pragma unroll
    for (int off = 32; off > 0; off >>= 1) sum += __shfl_xor(sum, off);
    if (lane < L_) alph[lane] = e / sum;
  }
  __syncthreads();
  const int d4 = dh * 256 + tid;
  const float4* sp4 = (const float4*)spatial;
  float4 acc = ((const float4*)h)[(long)b * 512 + d4];
#pragma unroll 7
  for (int l = 0; l < L_; ++l) {
    const float w = alph[l];
    const float4 v = sp4[((long)b * L_ + l) * 512 + d4];
    acc.x = fmaf(w, v.x, acc.x); acc.y = fmaf(w, v.y, acc.y);
    acc.z = fmaf(w, v.z, acc.z); acc.w = fmaf(w, v.w, acc.w);
  }
  short4 hv, lv;
  split1(acc.x, &hv.x, &lv.x); split1(acc.y, &hv.y, &lv.y);
  split1(acc.z, &hv.z, &lv.z); split1(acc.w, &hv.w, &lv.w);
  *(short4*)&a_hi[(long)b * D_ + d4*4] = hv;
  *(short4*)&a_lo[(long)b * D_ + d4*4] = lv;
}

// fallback monolithic attn
template<int SHG>
__global__ __launch_bounds__(256)
void attn_k(const float* __restrict__ sp_proj, const float* __restrict__ hgp,
            const float* __restrict__ w_h, const float* __restrict__ spatial,
            const float* __restrict__ h,
            short* __restrict__ a_hi, short* __restrict__ a_lo)
{
  const int b = blockIdx.x, half = blockIdx.y, tid = threadIdx.x;
  const int lane = tid & 63, wv = tid >> 6;
  __shared__ float hgs[KA_];
  __shared__ float whs[KA_];
  __shared__ float zs[L_];
  __shared__ float alph[L_];
  for (int i = tid; i < KA_; i += 256) {
    float s = 0.f;
#pragma unroll
    for (int sl = 0; sl < SHG; ++sl) s += hgp[((long)sl * B_ + b) * KA_ + i];
    hgs[i] = s; whs[i] = w_h[i];
  }
  __syncthreads();
  for (int l = wv; l < L_; l += 4) {
    const float* sp = sp_proj + ((long)b * L_ + l) * KA_;
    float s = 0.f;
    for (int k = lane; k < KA_; k += 64) s += whs[k] * tanhf(sp[k] + hgs[k]);
#pragma unroll
    for (int off = 32; off > 0; off >>= 1) s += __shfl_down(s, off);
    if (lane == 0) zs[l] = s;
  }
  __syncthreads();
  if (wv == 0) {
    float v = (lane < L_) ? zs[lane] : -INFINITY;
    float mx = v;
#pragma unroll
    for (int off = 32; off > 0; off >>= 1) mx = fmaxf(mx, __shfl_xor(mx, off));
    float e = (lane < L_) ? expf(v - mx) : 0.f;
    float sum = e;
#pragma unroll
    for (int off = 32; off > 0; off >>= 1) sum += __shfl_xor(sum, off);
    if (lane < L_) alph[lane] = e / sum;
  }
  __syncthreads();
  const int d4 = half * 256 + tid;
  const float4* h4 = (const float4*)h;
  const float4* sp4 = (const float4*)spatial;
  float4 acc = h4[(long)b * 512 + d4];
#pragma unroll 7
  for (int l = 0; l < L_; ++l) {
    const float w = alph[l];
    const float4 v = sp4[((long)b * L_ + l) * 512 + d4];
    acc.x = fmaf(w, v.x, acc.x); acc.y = fmaf(w, v.y, acc.y);
    acc.z = fmaf(w, v.z, acc.z); acc.w = fmaf(w, v.w, acc.w);
  }
  short4 hv, lv;
  split1(acc.x, &hv.x, &lv.x); split1(acc.y, &hv.y, &lv.y);
  split1(acc.z, &hv.z, &lv.z); split1(acc.w, &hv.w, &lv.w);
  *(short4*)&a_hi[(long)b * D_ + d4*4] = hv;
  *(short4*)&a_lo[(long)b * D_ + d4*4] = lv;
}

// ---- parallel logits reduce + argmax (R11/R12-proven) ----
template<int S>
__global__ __launch_bounds__(256)
void logits_part_k(const float* __restrict__ lp, const float* __restrict__ bias,
                   float* __restrict__ outL, float* __restrict__ cval,
                   int* __restrict__ cidx)
{
  const int b = blockIdx.x, s8 = blockIdx.y, tid = threadIdx.x;
  const int j0 = s8 * 1264;
  float bv = -INFINITY; int bi = 0x7fffffff;
  for (int j = j0 + tid; j < j0 + 1264; j += 256) {
    if (j < V_) {
      float v = bias[j];
#pragma unroll
      for (int sl = 0; sl < S; ++sl) v += lp[((long)sl * B_ + b) * VP_ + j];
      outL[(long)b * (T_*V_) + j] = v;
      if (v > bv) { bv = v; bi = j; }
    }
  }
  __shared__ float sv[256];
  __shared__ int   si[256];
  sv[tid] = bv; si[tid] = bi;
  __syncthreads();
  for (int s = 128; s > 0; s >>= 1) {
    if (tid < s) {
      const float ov = sv[tid + s]; const int oi = si[tid + s];
      if (ov > sv[tid] || (ov == sv[tid] && oi < si[tid])) { sv[tid] = ov; si[tid] = oi; }
    }
    __syncthreads();
  }
  if (tid == 0) { cval[b*8 + s8] = sv[0]; cidx[b*8 + s8] = si[0]; }
}

__global__ __launch_bounds__(256)
void argmax_fin_k(const float* __restrict__ cval, const int* __restrict__ cidx,
                  int* __restrict__ tok, float* __restrict__ tokout,
                  const float* __restrict__ embed,
                  short* __restrict__ xe_hi, short* __restrict__ xe_lo)
{
  const int b = blockIdx.x, tid = threadIdx.x;
  __shared__ int stk;
  if (tid == 0) {
    float bv = cval[b*8]; int bi = cidx[b*8];
#pragma unroll
    for (int s = 1; s < 8; ++s) {
      const float v = cval[b*8 + s]; const int i = cidx[b*8 + s];
      if (v > bv || (v == bv && i < bi)) { bv = v; bi = i; }
    }
    tok[b] = bi; tokout[(long)b * T_] = (float)bi; stk = bi;
  }
  __syncthreads();
  const float* e = embed + (long)stk * E_;
  for (int i = tid; i < E_; i += 256)
    split1(e[i], &xe_hi[(long)b*E_ + i], &xe_lo[(long)b*E_ + i]);
}

// fallback monolithic logits+argmax
template<int S>
__global__ __launch_bounds__(256)
void logits_argmax_k(const float* __restrict__ lp, const float* __restrict__ bias,
                     float* __restrict__ outL, int* __restrict__ tok,
                     float* __restrict__ tokout)
{
  const int b = blockIdx.x, tid = threadIdx.x;
  float bv = -INFINITY; int bi = 0x7fffffff;
  for (int j = tid; j < V_; j += 256) {
    float v = bias[j];
#pragma unroll
    for (int sl = 0; sl < S; ++sl) v += lp[((long)sl * B_ + b) * VP_ + j];
    outL[(long)b * (T_*V_) + j] = v;
    if (v > bv) { bv = v; bi = j; }
  }
  __shared__ float sv[256];
  __shared__ int   si[256];
  sv[tid] = bv; si[tid] = bi;
  __syncthreads();
  for (int s = 128; s > 0; s >>= 1) {
    if (tid < s) {
      const float ov = sv[tid + s]; const int oi = si[tid + s];
      if (ov > sv[tid] || (ov == sv[tid] && oi < si[tid])) { sv[tid] = ov; si[tid] = oi; }
    }
    __syncthreads();
  }
  if (tid == 0) { tok[b] = si[0]; tokout[(long)b * T_] = (float)si[0]; }
}

// ============ host ============
extern "C" void kernel_launch(void* const* d_in, const int* in_sizes, int n_in,
                              void* d_out, int out_size, void* d_ws, size_t ws_size,
                              hipStream_t stream)
{
  const float* spatial  = (const float*)d_in[0];
  const float* global_  = (const float*)d_in[1];
  const float* embed    = (const float*)d_in[2];
  const float* W_ih     = (const float*)d_in[3];
  const float* W_hh     = (const float*)d_in[4];
  const float* b_ih     = (const float*)d_in[5];
  const float* b_hh     = (const float*)d_in[6];
  const float* W_v      = (const float*)d_in[7];
  const float* W_g      = (const float*)d_in[8];
  const float* w_h      = (const float*)d_in[9];
  const float* W_p_w    = (const float*)d_in[10];
  const float* W_p_b    = (const float*)d_in[11];
  const float* W_init_h = (const float*)d_in[12];
  const float* W_init_m = (const float*)d_in[13];
  float* out = (float*)d_out;
  float* tokout = out + (long)B_ * T_ * V_;

  char* base = (char*)d_ws;
  const size_t NEED_PRE = 284983808;
  const size_t NEED_FB  = 62390784;
  if (ws_size < NEED_FB) return;

  if (ws_size >= NEED_PRE) {
    float* sp      = (float*)(base + 0);           // 12,845,056
    float* h       = (float*)(base + 12845056);    //  1,048,576
    float* m       = (float*)(base + 13893632);    //  1,048,576
    short* h_hi    = (short*)(base + 14942208);    //    524,288
    short* h_lo    = (short*)(base + 15466496);
    short* a_hi    = (short*)(base + 15990784);
    short* a_lo    = (short*)(base + 16515072);
    short* xe_hi   = (short*)(base + 17039360);    //    131,072
    short* xe_lo   = (short*)(base + 17170432);
    short* g_hi    = (short*)(base + 18350080);    //    524,288
    short* g_lo    = (short*)(base + 18874368);
    float* gconst  = (float*)(base + 19398656);    //  4,194,304
    int*   tok     = (int*)  (base + 23592960);    //        512
    float* arena   = (float*)(base + 23593472);    // 83,886,080
    short* Wcat_hi = (short*)(base + 107479552);   // 41,943,040 (8192 x 2560)
    short* Wcat_lo = (short*)(base + 149422592);
    short* Wp_hi   = (short*)(base + 191365632);   // 41,418,752 (10112 x 2048)
    short* Wp_lo   = (short*)(base + 232784384);
    short* WvT_hi  = (short*)(base + 274203136);   //  2,097,152
    short* WvT_lo  = (short*)(base + 276300288);
    short* WgT_hi  = (short*)(base + 278397440);
    short* WgT_lo  = (short*)(base + 280494592);
    float* cval    = (float*)(base + 282886656);   //      4,096
    int*   cidx    = (int*)  (base + 282890752);   //      4,096

    init_tok_k<<<1, 128, 0, stream>>>(tok);
    split_plane_k<<<256, 256, 0, stream>>>(global_, (long)B_*D_, g_hi, g_lo);

    // ---- sp = spatial @ W_v (gemm_lds S=4, k_len=512) ----
    split_t_k<<<dim3(KA_/64, D_/64), 256, 0, stream>>>(W_v, D_, KA_, WvT_hi, WvT_lo);
    short* spA_hi = Wp_hi;
    short* spA_lo = (short*)((char*)Wp_hi + 25690112);
    split_plane_k<<<12544, 256, 0, stream>>>(spatial, (long)B_*L_*D_, spA_hi, spA_lo);
    float* sppart = (float*)Wcat_hi;
    gemm_lds<<<dim3(4, 4, 49), 256, 0, stream>>>(
        spA_hi, spA_lo, D_, spA_hi, spA_lo, D_, 1<<30,
        WvT_hi, WvT_lo, D_, sppart, B_*L_, KA_, 512);
    reduce_sp_k<4><<<3136, 256, 0, stream>>>((const float4*)sppart, (float4*)sp);

    // ---- gconst = global_ @ W_ih[:,512:]^T + b_ih + b_hh (gemm_lds S=8) ----
    short* Wglob_hi = Wp_hi;
    short* Wglob_lo = (short*)((char*)Wp_hi + 33554432);
    split_nt_k<<<dim3(2, H4_), 256, 0, stream>>>(W_ih + 512, ED_, H4_, D_, Wglob_hi, Wglob_lo, D_, 0);
    gemm_lds<<<dim3(64, 8, 1), 256, 0, stream>>>(
        g_hi, g_lo, D_, g_hi, g_lo, D_, 1<<30,
        Wglob_hi, Wglob_lo, D_, arena, B_, H4_, 256);
    gred_k<8><<<(B_*H4_)/256, 256, 0, stream>>>(arena, b_ih, b_hh, gconst);

    // ---- loop weight planes ----
    split_nt_k<<<dim3(1, H4_), 256, 0, stream>>>(W_ih, ED_, H4_, E_, Wcat_hi, Wcat_lo, KT2_, 0);
    split_nt_k<<<dim3(2, H4_), 256, 0, stream>>>(W_hh, H_, H4_, H_, Wcat_hi, Wcat_lo, KT2_, E_);
    split_nt_k<<<dim3(2, VP_), 256, 0, stream>>>(W_p_w, H_, V_, H_, Wp_hi, Wp_lo, H_, 0);
    split_t_k<<<dim3(KA_/64, H_/64), 256, 0, stream>>>(W_g, H_, KA_, WgT_hi, WgT_lo);

    // ---- h0/m0 (gemm_lds S=16, k_len=128) ----
    {
      short* WTh = (short*)arena;
      short* WTl = (short*)((char*)arena + 8388608);
      float* prt = (float*)((char*)arena + 16777216);
      split_t_k<<<dim3(H_/64, D_/64), 256, 0, stream>>>(W_init_h, D_, H_, WTh, WTl);
      gemm_lds<<<dim3(16, 16, 1), 256, 0, stream>>>(
          g_hi, g_lo, D_, g_hi, g_lo, D_, 1<<30,
          WTh, WTl, D_, prt, B_, H_, 128);
      reduce_tanh_k<<<(B_*H_)/256, 256, 0, stream>>>(prt, 16, h, h_hi, h_lo);
      split_t_k<<<dim3(H_/64, D_/64), 256, 0, stream>>>(W_init_m, D_, H_, WTh, WTl);
      gemm_lds<<<dim3(16, 16, 1), 256, 0, stream>>>(
          g_hi, g_lo, D_, g_hi, g_lo, D_, 1<<30,
          WTh, WTl, D_, prt, B_, H_, 128);
      reduce_tanh_k<<<(B_*H_)/256, 256, 0, stream>>>(prt, 16, m, nullptr, nullptr);
    }

    gather_emb_k<<<B_, 256, 0, stream>>>(embed, tok, xe_hi, xe_lo);

    for (int t = 0; t < T_; ++t) {
      // gates: A = [emb(512) | h(2048)], S=8, k_len=320
      gemm_lds<<<dim3(64, 8, 1), 256, 0, stream>>>(
          xe_hi, xe_lo, E_, h_hi, h_lo, H_, E_,
          Wcat_hi, Wcat_lo, KT2_, arena, B_, H4_, 320);
      lstm_reduce_k<8><<<(B_*H_)/256, 256, 0, stream>>>(
          arena, gconst, nullptr, nullptr, h, m, h_hi, h_lo);
      // hg: S=32, k_len=64
      gemm_lds<<<dim3(4, 32, 1), 256, 0, stream>>>(
          h_hi, h_lo, H_, h_hi, h_lo, H_, 1<<30,
          WgT_hi, WgT_lo, H_, arena, B_, KA_, 64);
      // fused attention (hg-reduce + z + softmax + c + comb)
      attn_one<<<dim3(B_, 2), 256, 0, stream>>>(arena, sp, w_h, spatial, h, a_hi, a_lo);
      // logits: S=8, k_len=256
      gemm_lds<<<dim3(79, 8, 1), 256, 0, stream>>>(
          a_hi, a_lo, H_, a_hi, a_lo, H_, 1<<30,
          Wp_hi, Wp_lo, H_, arena, B_, VP_, 256);
      logits_part_k<8><<<dim3(B_, 8), 256, 0, stream>>>(
          arena, W_p_b, out + (long)t * V_, cval, cidx);
      argmax_fin_k<<<B_, 256, 0, stream>>>(
          cval, cidx, tok, tokout + t, embed, xe_hi, xe_lo);
    }
  } else {
    // -------- fallback: fp32 weights, on-the-fly split --------
    float* sp    = (float*)(base + 0);
    float* WvTf  = (float*)(base + 12845056);
    float* WgTf  = (float*)(base + 17039360);
    float* h     = (float*)(base + 21233664);
    float* m     = (float*)(base + 22282240);
    short* h_hi  = (short*)(base + 24379392);
    short* h_lo  = (short*)(base + 24903680);
    short* a_hi  = (short*)(base + 25427968);
    short* a_lo  = (short*)(base + 25952256);
    short* xh_hi = (short*)(base + 26476544);
    short* xh_lo = (short*)(base + 27656192);
    int*   tok   = (int*)  (base + 28835840);
    float* arena = (float*)(base + 28836352);

    init_tok_k<<<1, 128, 0, stream>>>(tok);
    transpose_f32<<<dim3(KA_/64, D_/64), 256, 0, stream>>>(W_v, D_, KA_, WvTf);
    gemm_mfma<true><<<dim3(4, 1, 49), 256, 0, stream>>>(
        spatial, nullptr, D_, WvTf, D_, nullptr, 0, 1<<30, sp, B_*L_, KA_, KA_, D_);
    transpose_f32<<<dim3(KA_/64, H_/64), 256, 0, stream>>>(W_g, H_, KA_, WgTf);
    {
      float* WT  = arena;
      float* prt = (float*)((char*)arena + 16777216);
      transpose_f32<<<dim3(H_/64, D_/64), 256, 0, stream>>>(W_init_h, D_, H_, WT);
      gemm_mfma<true><<<dim3(16, 4, 1), 256, 0, stream>>>(
          global_, nullptr, D_, WT, D_, nullptr, 0, 1<<30, prt, B_, H_, H_, 512);
      reduce_tanh_k<<<(B_*H_)/256, 256, 0, stream>>>(prt, 4, h, h_hi, h_lo);
      transpose_f32<<<dim3(H_/64, D_/64), 256, 0, stream>>>(W_init_m, D_, H_, WT);
      gemm_mfma<true><<<dim3(16, 4, 1), 256, 0, stream>>>(
          global_, nullptr, D_, WT, D_, nullptr, 0, 1<<30, prt, B_, H_, H_, 512);
      reduce_tanh_k<<<(B_*H_)/256, 256, 0, stream>>>(prt, 4, m, nullptr, nullptr);
    }
    for (int t = 0; t < T_; ++t) {
      gather_xh_k<<<B_, 256, 0, stream>>>(embed, global_, h_hi, h_lo, tok, xh_hi, xh_lo);
      gemm_mfma<false><<<dim3(64, 8, 1), 256, 0, stream>>>(
          xh_hi, xh_lo, KT_, W_ih, ED_, W_hh, H_, ED_, arena, B_, H4_, H4_, 576);
      lstm_reduce_k<8><<<(B_*H_)/256, 256, 0, stream>>>(
          arena, nullptr, b_ih, b_hh, h, m, h_hi, h_lo);
      gemm_mfma<false><<<dim3(4, 16, 1), 256, 0, stream>>>(
          h_hi, h_lo, H_, WgTf, H_, nullptr, 0, 1<<30, arena, B_, KA_, KA_, 128);
      attn_k<16><<<dim3(B_, 2), 256, 0, stream>>>(sp, arena, w_h, spatial, h, a_hi, a_lo);
      gemm_mfma<false><<<dim3(79, 4, 1), 256, 0, stream>>>(
          a_hi, a_lo, H_, W_p_w, H_, nullptr, 0, 1<<30, arena, B_, VP_, V_, 512);
      logits_argmax_k<4><<<B_, 256, 0, stream>>>(
          arena, W_p_b, out + (long)t * V_, tok, tokout + t);
    }
  }
}